// Round 5
// baseline (237.175 us; speedup 1.0000x reference)
//
#include <hip/hip_runtime.h>

#define NB   512
#define NN   50
#define LLn  50
#define HD   128
#define OUTN 99999
#define RTOT 25600

// ---------------- ws byte offsets ----------------
#define WS_W1T   0         // fp32 [128][128] transposed
#define WS_W2T   65536     // fp32 [128][128] transposed
#define WS_WTT   131072    // fp32 [256][128] transposed
#define WS_WEH   262144    // bf16 hi [256 n][128 k]  (rows 0-127 W_ein, 128-255 W_eout)
#define WS_WEL   327680    // bf16 lo
#define WS_WCATH 393216    // bf16 hi [384 n][384 k]  (k<256 w_ih, k>=256 w_hh)
#define WS_WCATL 688128    // bf16 lo
#define WS_AHI   983040    // a-final hi image [2 kh][512 b][128 B]
#define WS_ALO   1114112
// IN images: [2 kh][25600 rows][256 B] pre-swizzled bf16
#define WS_INH   1245184
#define WS_INL   14352384
// H images: [25600 rows][256 B] pre-swizzled bf16
#define WS_HBH   27459584
#define WS_HBL   34013184

// ---------------- d_out scratch offsets (floats) ----------------
#define SC_H    0          // hidden fp32 [25600][128]
#define SC_H2   3276800    // new hidden fp32 [25600][128]

typedef __attribute__((ext_vector_type(8))) short bf16x8;
typedef __attribute__((ext_vector_type(4))) float f32x4;

__device__ __forceinline__ unsigned short f2bf(float f) {
  unsigned int u = __float_as_uint(f);
  unsigned int r = (u + 0x7FFFu + ((u >> 16) & 1u)) >> 16;
  return (unsigned short)r;
}
__device__ __forceinline__ float bf2f(unsigned short h) {
  return __uint_as_float(((unsigned int)h) << 16);
}
__device__ __forceinline__ void cvt4(float4 v, ushort4& hi, ushort4& lo) {
  unsigned short h0 = f2bf(v.x), h1 = f2bf(v.y), h2 = f2bf(v.z), h3 = f2bf(v.w);
  hi = make_ushort4(h0, h1, h2, h3);
  lo = make_ushort4(f2bf(v.x - bf2f(h0)), f2bf(v.y - bf2f(h1)),
                    f2bf(v.z - bf2f(h2)), f2bf(v.w - bf2f(h3)));
}
__device__ __forceinline__ void gl_lds16(const void* g, void* l) {
  __builtin_amdgcn_global_load_lds(
      (const __attribute__((address_space(1))) void*)g,
      (__attribute__((address_space(3))) void*)l, 16, 0, 0);
}

// ================= k0: weight prep =================
__global__ void k0_prep(const float* __restrict__ w_ih, const float* __restrict__ w_hh,
                        const float* __restrict__ W_ein, const float* __restrict__ W_eout,
                        const float* __restrict__ W1, const float* __restrict__ W2,
                        const float* __restrict__ Wt, char* __restrict__ wsb)
{
  float* wsf = (float*)wsb;
  for (int i = blockIdx.x * blockDim.x + threadIdx.x; i < 245760; i += gridDim.x * blockDim.x) {
    int idx = i;
    if (idx < 16384) { int k = idx >> 7, c = idx & 127; wsf[idx] = W1[c*128 + k]; continue; }
    idx -= 16384;
    if (idx < 16384) { int k = idx >> 7, c = idx & 127; wsf[16384 + idx] = W2[c*128 + k]; continue; }
    idx -= 16384;
    if (idx < 32768) { int k = idx >> 7, c = idx & 127; wsf[32768 + idx] = Wt[c*256 + k]; continue; }
    idx -= 32768;
    if (idx < 32768) {
      int n = idx >> 7, k = idx & 127;
      float v = (n < 128) ? W_ein[n*128 + k] : W_eout[(n-128)*128 + k];
      unsigned short h = f2bf(v);
      *(unsigned short*)(wsb + WS_WEH + idx*2) = h;
      *(unsigned short*)(wsb + WS_WEL + idx*2) = f2bf(v - bf2f(h));
      continue;
    }
    idx -= 32768;
    {
      // concat weight: [384 n][384 k], k<256 -> w_ih, k>=256 -> w_hh
      int n = idx / 384, k = idx % 384;
      float v = (k < 256) ? w_ih[n*256 + k] : w_hh[n*128 + (k - 256)];
      unsigned short h = f2bf(v);
      *(unsigned short*)(wsb + WS_WCATH + idx*2) = h;
      *(unsigned short*)(wsb + WS_WCATL + idx*2) = f2bf(v - bf2f(h));
    }
  }
}

// ====== k1ab: per-sample gather + he GEMM (M=64,N=256,K=128) + A@he, emits
//        H fp32, H bf16-images, IN bf16-images (pre-swizzled). 512 thr, 1 sample/blk.
__global__ __launch_bounds__(512) void k1ab(const int* __restrict__ items,
    const float* __restrict__ A, const float* __restrict__ emb,
    const float* __restrict__ b_ein, const float* __restrict__ b_eout,
    const float* __restrict__ b_iah, const float* __restrict__ b_oah,
    char* __restrict__ wsb, float* __restrict__ outf)
{
  extern __shared__ char lds[];
  float* HID = (float*)lds;                    // [50][128] fp32  = 25600 B
  char*  AH  = lds + 25600;                    // [64][128] bf16  = 16384 B
  char*  AL  = lds + 25600 + 16384;            // 16384 B
  float* HE  = (float*)(lds + 58368);          // [50][256] fp32  = 51200 B
  float* A_l = (float*)(lds + 109568);         // [2][50][52] fp32 = 20800 B -> total 130368

  const int b = blockIdx.x, tid = threadIdx.x;
  const int lane = tid & 63, wid = tid >> 6, l15 = lane & 15, lq = lane >> 4;

  // ---- gather + H outputs + he-GEMM A-stage ----
  for (int i = tid; i < 1600; i += 512) {
    int row = i >> 5, part = i & 31;
    int it = items[b*NN + row];
    float4 v = *(const float4*)&emb[(size_t)it*128 + part*4];
    *(float4*)&HID[row*128 + part*4] = v;
    *(float4*)&outf[SC_H + ((size_t)b*NN + row)*128 + part*4] = v;
    ushort4 h4, g4;
    cvt4(v, h4, g4);
    unsigned off = row*256 + (((unsigned)(part*8)) ^ (((unsigned)(row&7)) << 4));
    *(ushort4*)(AH + off) = h4;
    *(ushort4*)(AL + off) = g4;
    size_t grow = (size_t)b*NN + row;
    unsigned gb = ((unsigned)(part*8)) ^ (((unsigned)(grow&7)) << 4);
    *(ushort4*)(wsb + WS_HBH + grow*256 + gb) = h4;
    *(ushort4*)(wsb + WS_HBL + grow*256 + gb) = g4;
  }
  // zero-pad A-stage rows 50..63
  for (int i = tid; i < 224; i += 512) {
    int row = 50 + (i >> 4), part = i & 15;
    unsigned off = row*256 + (((unsigned)(part*16)) ^ (((unsigned)(row&7)) << 4));
    *(ushort4*)(AH + off) = make_ushort4(0,0,0,0);
    *(ushort4*)(AL + off) = make_ushort4(0,0,0,0);
  }
  // stage adjacency
  const float* Ab = A + (size_t)b*NN*100;
  for (int i = tid; i < 5000; i += 512) {
    int n = i / 100, cc = i % 100;
    int s_ = (cc >= 50) ? 1 : 0, m = cc - s_*50;
    A_l[s_*2600 + n*52 + m] = Ab[i];
  }
  __syncthreads();

  // ---- he GEMM: 8 waves, each 64 rows x 32 cols ----
  {
    f32x4 acc[4][2];
#pragma unroll
    for (int i = 0; i < 4; ++i) { acc[i][0] = (f32x4){0,0,0,0}; acc[i][1] = (f32x4){0,0,0,0}; }
    for (int s = 0; s < 4; ++s) {
      bf16x8 ah[4], al[4];
#pragma unroll
      for (int i = 0; i < 4; ++i) {
        int row = i*16 + l15;
        unsigned off = row*256 + (((unsigned)(s*64 + lq*16)) ^ (((unsigned)(row&7)) << 4));
        ah[i] = *(const bf16x8*)(AH + off);
        al[i] = *(const bf16x8*)(AL + off);
      }
#pragma unroll
      for (int j = 0; j < 2; ++j) {
        int n = wid*32 + j*16 + l15;
        unsigned boff = (unsigned)(n*256 + s*64 + lq*16);
        bf16x8 bh = *(const bf16x8*)(wsb + WS_WEH + boff);
        bf16x8 bl = *(const bf16x8*)(wsb + WS_WEL + boff);
#pragma unroll
        for (int i = 0; i < 4; ++i) {
          acc[i][j] = __builtin_amdgcn_mfma_f32_16x16x32_bf16(ah[i], bh, acc[i][j], 0,0,0);
          acc[i][j] = __builtin_amdgcn_mfma_f32_16x16x32_bf16(ah[i], bl, acc[i][j], 0,0,0);
          acc[i][j] = __builtin_amdgcn_mfma_f32_16x16x32_bf16(al[i], bh, acc[i][j], 0,0,0);
        }
      }
    }
#pragma unroll
    for (int j = 0; j < 2; ++j) {
      int n = wid*32 + j*16 + l15;
      float bias = (n < 128) ? b_ein[n] : b_eout[n - 128];
#pragma unroll
      for (int i = 0; i < 4; ++i) {
        int rb = i*16 + lq*4;
#pragma unroll
        for (int q = 0; q < 4; ++q) {
          int row = rb + q;
          if (row < 50) HE[row*256 + n] = acc[i][j][q] + bias;
        }
      }
    }
  }
  __syncthreads();

  // ---- A@he (VALU): thread = (th n-half, sel in/out, c) ----
  {
    const int c = tid & 127, sel = (tid >> 7) & 1, th = tid >> 8;
    const float* Asel = A_l + sel*2600;
    const float* hes  = HE + sel*128 + c;
    const int nbase = th*25;
    float acc[25];
#pragma unroll
    for (int n = 0; n < 25; ++n) acc[n] = 0.f;
    for (int m4 = 0; m4 < 48; m4 += 4) {
      float x0 = hes[(m4+0)*256], x1 = hes[(m4+1)*256];
      float x2 = hes[(m4+2)*256], x3 = hes[(m4+3)*256];
#pragma unroll
      for (int n = 0; n < 25; ++n) {
        float4 a = *(const float4*)&Asel[(nbase+n)*52 + m4];
        acc[n] += a.x*x0 + a.y*x1 + a.z*x2 + a.w*x3;
      }
    }
    {
      float x0 = hes[48*256], x1 = hes[49*256];
#pragma unroll
      for (int n = 0; n < 25; ++n)
        acc[n] += Asel[(nbase+n)*52 + 48]*x0 + Asel[(nbase+n)*52 + 49]*x1;
    }
    float bias = sel ? b_oah[c] : b_iah[c];
#pragma unroll
    for (int n = 0; n < 25; ++n) {
      float v = acc[n] + bias;
      size_t grow = (size_t)b*NN + nbase + n;
      unsigned short hi = f2bf(v);
      unsigned short lo = f2bf(v - bf2f(hi));
      unsigned gb = ((unsigned)(c*2)) ^ (((unsigned)(grow&7)) << 4);
      *(unsigned short*)(wsb + WS_INH + (size_t)sel*6553600 + grow*256 + gb) = hi;
      *(unsigned short*)(wsb + WS_INL + (size_t)sel*6553600 + grow*256 + gb) = lo;
    }
  }
}

// ====== k1cd: [IN | H] @ [w_ih|w_hh]^T (M=128/blk, K=384) + GRU epilogue.
//        A-chunks staged via global_load_lds from pre-swizzled images, 2-phase dbuf.
__global__ __launch_bounds__(512) void k1cd_gru2(const char* __restrict__ wsb,
    const float* __restrict__ b_ih, const float* __restrict__ b_hh,
    float* __restrict__ outf)
{
  extern __shared__ char lds[];   // 2 x (AH 32K | AL 32K) = 131072
  const float* H  = outf + SC_H;
  float* H2 = outf + SC_H2;
  const int tid = threadIdx.x, lane = tid & 63, wid = tid >> 6;
  const int wm = wid >> 2, wn = wid & 3, l15 = lane & 15, lq = lane >> 4;
  const int r0 = blockIdx.x * 128;

  auto stage = [&](int kh, int buf) {
    char* dH = lds + buf*65536;
    char* dL = dH + 32768;
    const char* sH;
    const char* sL;
    if (kh < 2) {
      sH = wsb + WS_INH + (size_t)kh*6553600 + (size_t)r0*256;
      sL = wsb + WS_INL + (size_t)kh*6553600 + (size_t)r0*256;
    } else {
      sH = wsb + WS_HBH + (size_t)r0*256;
      sL = wsb + WS_HBL + (size_t)r0*256;
    }
#pragma unroll
    for (int r = 0; r < 4; ++r) {
      int off = (r*512 + tid) * 16;
      gl_lds16(sH + off, dH + off);
      gl_lds16(sL + off, dL + off);
    }
  };

  f32x4 acc[4][6];   // r,i merged K=384; slots 4,5 = gi_n
  f32x4 accn[4][2];  // gh_n
#pragma unroll
  for (int i = 0; i < 4; ++i) {
#pragma unroll
    for (int j = 0; j < 6; ++j) acc[i][j] = (f32x4){0.f,0.f,0.f,0.f};
    accn[i][0] = (f32x4){0.f,0.f,0.f,0.f};
    accn[i][1] = (f32x4){0.f,0.f,0.f,0.f};
  }

  stage(0, 0);
  __syncthreads();

  for (int kh = 0; kh < 3; ++kh) {
    if (kh < 2) stage(kh + 1, (kh + 1) & 1);   // prefetch next chunk (in flight during MFMA)
    char* AH = lds + (kh & 1)*65536;
    char* AL = AH + 32768;

    for (int s = 0; s < 4; ++s) {
      bf16x8 ah[4], al[4];
#pragma unroll
      for (int i = 0; i < 4; ++i) {
        int row = wm*64 + i*16 + l15;
        unsigned off = row*256 + (((unsigned)(s*64 + lq*16)) ^ (((unsigned)(row&7)) << 4));
        ah[i] = *(const bf16x8*)(AH + off);
        al[i] = *(const bf16x8*)(AL + off);
      }
      // gates r,i: merged K=384
#pragma unroll
      for (int g = 0; g < 2; ++g)
#pragma unroll
        for (int j2 = 0; j2 < 2; ++j2) {
          int n = g*128 + wn*32 + j2*16 + l15;
          unsigned boff = (unsigned)(n*768 + kh*256 + s*64 + lq*16);
          bf16x8 bh = *(const bf16x8*)(wsb + WS_WCATH + boff);
          bf16x8 bl = *(const bf16x8*)(wsb + WS_WCATL + boff);
#pragma unroll
          for (int i = 0; i < 4; ++i) {
            acc[i][g*2+j2] = __builtin_amdgcn_mfma_f32_16x16x32_bf16(ah[i], bh, acc[i][g*2+j2], 0,0,0);
            acc[i][g*2+j2] = __builtin_amdgcn_mfma_f32_16x16x32_bf16(ah[i], bl, acc[i][g*2+j2], 0,0,0);
            acc[i][g*2+j2] = __builtin_amdgcn_mfma_f32_16x16x32_bf16(al[i], bh, acc[i][g*2+j2], 0,0,0);
          }
        }
      // gate n: gi part (kh<2) and gh part (kh==2) kept separate
#pragma unroll
      for (int j2 = 0; j2 < 2; ++j2) {
        int n = 256 + wn*32 + j2*16 + l15;
        unsigned boff = (unsigned)(n*768 + kh*256 + s*64 + lq*16);
        bf16x8 bh = *(const bf16x8*)(wsb + WS_WCATH + boff);
        bf16x8 bl = *(const bf16x8*)(wsb + WS_WCATL + boff);
        if (kh < 2) {
#pragma unroll
          for (int i = 0; i < 4; ++i) {
            acc[i][4+j2] = __builtin_amdgcn_mfma_f32_16x16x32_bf16(ah[i], bh, acc[i][4+j2], 0,0,0);
            acc[i][4+j2] = __builtin_amdgcn_mfma_f32_16x16x32_bf16(ah[i], bl, acc[i][4+j2], 0,0,0);
            acc[i][4+j2] = __builtin_amdgcn_mfma_f32_16x16x32_bf16(al[i], bh, acc[i][4+j2], 0,0,0);
          }
        } else {
#pragma unroll
          for (int i = 0; i < 4; ++i) {
            accn[i][j2] = __builtin_amdgcn_mfma_f32_16x16x32_bf16(ah[i], bh, accn[i][j2], 0,0,0);
            accn[i][j2] = __builtin_amdgcn_mfma_f32_16x16x32_bf16(ah[i], bl, accn[i][j2], 0,0,0);
            accn[i][j2] = __builtin_amdgcn_mfma_f32_16x16x32_bf16(al[i], bh, accn[i][j2], 0,0,0);
          }
        }
      }
    }
    __syncthreads();   // drains prefetch loads too (they had the MFMA phase to land)
  }

#pragma unroll
  for (int j2 = 0; j2 < 2; ++j2) {
    int c = wn*32 + j2*16 + l15;
    float bir = b_ih[c], bii = b_ih[128+c], bin_ = b_ih[256+c];
    float bhr = b_hh[c], bhi = b_hh[128+c], bhn  = b_hh[256+c];
#pragma unroll
    for (int i = 0; i < 4; ++i) {
      int rb = r0 + wm*64 + i*16 + lq*4;
#pragma unroll
      for (int q = 0; q < 4; ++q) {
        size_t r = (size_t)(rb + q);
        float rg = 1.f/(1.f + __expf(-(acc[i][j2][q]   + bir + bhr)));
        float ig = 1.f/(1.f + __expf(-(acc[i][2+j2][q] + bii + bhi)));
        float ng = tanhf(acc[i][4+j2][q] + bin_ + rg*(accn[i][j2][q] + bhn));
        float h = H[r*128 + c];
        H2[r*128 + c] = ng + ig*(h - ng);
      }
    }
  }
}

// ================= k1e: per-sample attention readout (all-lane parallel) ==========
__global__ __launch_bounds__(256) void k1e_attn(const int* __restrict__ alias_in,
    const float* __restrict__ b1, const float* __restrict__ b2,
    const float* __restrict__ W3, const float* __restrict__ bt_,
    char* __restrict__ wsb, const float* __restrict__ outf)
{
  extern __shared__ float s[];
  float* S_hid   = s;            // 6400
  float* S_sig   = s + 6400;     // 50*132 = 6600
  float* S_q1p   = s + 13000;    // 256
  float* S_ap    = s + 13256;    // 256
  float* S_rp    = s + 13512;    // 256
  float* S_alpha = s + 13768;    // 64
  int*   S_alias = (int*)(s + 13832); // 64

  const int b = blockIdx.x, tid = threadIdx.x;
  const int c = tid & 127, h = tid >> 7;
  const float* H2  = outf + SC_H2;
  const float* W1T = (const float*)(wsb + WS_W1T);
  const float* W2T = (const float*)(wsb + WS_W2T);
  const float* WtT = (const float*)(wsb + WS_WTT);

  const float4* h4 = (const float4*)(H2 + (size_t)b*NN*HD);
  for (int i = tid; i < 1600; i += 256) ((float4*)S_hid)[i] = h4[i];
  if (tid < LLn) S_alias[tid] = alias_in[b*LLn + tid];
  __syncthreads();

  int cnt = 0;
  for (int l = 0; l < LLn; ++l) cnt += (S_alias[l] > 0) ? 1 : 0;
  int last = cnt - 1; if (last < 0) last = LLn - 1;
  const int a_last = S_alias[last];

  {
    float q = 0.f;
    for (int k = h*64; k < h*64 + 64; k += 4) {
      float4 x = *(const float4*)&S_hid[a_last*HD + k];
      q += x.x*W1T[(k<<7)+c] + x.y*W1T[((k+1)<<7)+c]
         + x.z*W1T[((k+2)<<7)+c] + x.w*W1T[((k+3)<<7)+c];
    }
    S_q1p[h*128 + c] = q;
  }
  __syncthreads();

  {
    int al_[25];
#pragma unroll
    for (int i = 0; i < 25; ++i) al_[i] = S_alias[2*i + h];
    float q2a[25];
#pragma unroll
    for (int i = 0; i < 25; ++i) q2a[i] = 0.f;
    for (int k = 0; k < HD; k += 4) {
      float w0 = W2T[(k<<7)+c],     w1 = W2T[((k+1)<<7)+c];
      float w2 = W2T[((k+2)<<7)+c], w3 = W2T[((k+3)<<7)+c];
#pragma unroll
      for (int i = 0; i < 25; ++i) {
        float4 x = *(const float4*)&S_hid[al_[i]*HD + k];
        q2a[i] += x.x*w0; q2a[i] += x.y*w1; q2a[i] += x.z*w2; q2a[i] += x.w*w3;
      }
    }
    float q1c = S_q1p[c] + S_q1p[128 + c] + b1[c] + b2[c];
#pragma unroll
    for (int i = 0; i < 25; ++i) {
      int l = 2*i + h;
      S_sig[l*132 + c] = 1.f/(1.f + __expf(-(q1c + q2a[i])));
    }
  }
  __syncthreads();

  if (tid < 200) {
    int l = tid >> 2, q = tid & 3;
    float sum = 0.f;
    for (int cc = q*32; cc < q*32 + 32; cc += 4) {
      float4 x = *(const float4*)&S_sig[l*132 + cc];
      sum += x.x*W3[cc] + x.y*W3[cc+1] + x.z*W3[cc+2] + x.w*W3[cc+3];
    }
    sum += __shfl_xor(sum, 1);
    sum += __shfl_xor(sum, 2);
    if (q == 0) S_alpha[l] = (S_alias[l] > 0) ? sum : 0.f;
  }
  __syncthreads();

  {
    float acc = 0.f;
    for (int l = h*25; l < h*25 + 25; ++l)
      acc += S_alpha[l] * S_hid[S_alias[l]*HD + c];
    S_ap[h*128 + c] = acc;
  }
  __syncthreads();

  {
    float r = 0.f;
    for (int k = h*64; k < h*64 + 64; ++k) {
      float av = S_ap[k] + S_ap[128 + k];
      r += av * WtT[(k<<7) + c] + S_hid[a_last*HD + k] * WtT[((128+k)<<7) + c];
    }
    S_rp[h*128 + c] = r;
  }
  __syncthreads();

  if (tid < 128) {
    float r = bt_[c] + S_rp[c] + S_rp[128 + c];
    int kh = c >> 6, kl = c & 63;
    unsigned int cb = (unsigned int)(kl*2) ^ (((unsigned int)(b & 7)) << 4);
    unsigned short hi = f2bf(r);
    unsigned short lo = f2bf(r - bf2f(hi));
    *(unsigned short*)(wsb + WS_AHI + kh*65536 + b*128 + cb) = hi;
    *(unsigned short*)(wsb + WS_ALO + kh*65536 + b*128 + cb) = lo;
  }
}

// ================= k2: scores GEMM, E-tile reused across both b-halves ============
__global__ __launch_bounds__(512) void k2_mfma(const float* __restrict__ emb,
                                               const char* __restrict__ wsb,
                                               float* __restrict__ out)
{
  extern __shared__ char ldsc[];
  char* AHI = ldsc;
  char* ALO = ldsc + 32768;
  char* EHI = ldsc + 65536;
  char* ELO = ldsc + 81920;

  const int tid  = threadIdx.x;
  const int lane = tid & 63;
  const int wid  = tid >> 6;
  const int wm   = wid >> 1;
  const int wn   = wid & 1;
  const int j0   = blockIdx.x * 128;
  const int l15  = lane & 15, lq = lane >> 4;

  f32x4 acc[2][4][4];
#pragma unroll
  for (int bi = 0; bi < 2; ++bi)
#pragma unroll
    for (int i = 0; i < 4; ++i)
#pragma unroll
      for (int j = 0; j < 4; ++j) acc[bi][i][j] = (f32x4){0.f, 0.f, 0.f, 0.f};

  for (int kh = 0; kh < 2; ++kh) {
    {
      int rbase = tid >> 4, c4 = tid & 15;
#pragma unroll
      for (int rr = 0; rr < 4; ++rr) {
        int row = rbase + rr*32;
        int j = j0 + row; if (j > OUTN - 1) j = OUTN - 1;
        float4 v = *(const float4*)&emb[(size_t)(1 + j)*HD + kh*64 + c4*4];
        ushort4 hi4, lo4;
        cvt4(v, hi4, lo4);
        unsigned int off = (unsigned int)(row*128) + (((unsigned int)(c4*8)) ^ (((unsigned int)(row&7)) << 4));
        *(ushort4*)(EHI + off) = hi4;
        *(ushort4*)(ELO + off) = lo4;
      }
    }
#pragma unroll
    for (int bi = 0; bi < 2; ++bi) {
      const char* srcH = wsb + WS_AHI + kh*65536 + bi*32768;
      const char* srcL = wsb + WS_ALO + kh*65536 + bi*32768;
#pragma unroll
      for (int r = 0; r < 4; ++r) {
        int off = (r*512 + tid) * 16;
        gl_lds16(srcH + off, AHI + off);
        gl_lds16(srcL + off, ALO + off);
      }
      __syncthreads();

#pragma unroll
      for (int s = 0; s < 2; ++s) {
        bf16x8 ah[4], al[4], bh[4], bl[4];
        const unsigned int cb = (unsigned int)(s*64 + (lq << 4));
#pragma unroll
        for (int i = 0; i < 4; ++i) {
          int row = wm*64 + i*16 + l15;
          unsigned int off = (unsigned int)(row*128) + (cb ^ (((unsigned int)(row&7)) << 4));
          ah[i] = *(const bf16x8*)(AHI + off);
          al[i] = *(const bf16x8*)(ALO + off);
        }
#pragma unroll
        for (int j = 0; j < 4; ++j) {
          int row = wn*64 + j*16 + l15;
          unsigned int off = (unsigned int)(row*128) + (cb ^ (((unsigned int)(row&7)) << 4));
          bh[j] = *(const bf16x8*)(EHI + off);
          bl[j] = *(const bf16x8*)(ELO + off);
        }
#pragma unroll
        for (int i = 0; i < 4; ++i)
#pragma unroll
          for (int j = 0; j < 4; ++j) {
            acc[bi][i][j] = __builtin_amdgcn_mfma_f32_16x16x32_bf16(ah[i], bh[j], acc[bi][i][j], 0, 0, 0);
            acc[bi][i][j] = __builtin_amdgcn_mfma_f32_16x16x32_bf16(ah[i], bl[j], acc[bi][i][j], 0, 0, 0);
            acc[bi][i][j] = __builtin_amdgcn_mfma_f32_16x16x32_bf16(al[i], bh[j], acc[bi][i][j], 0, 0, 0);
          }
      }
      __syncthreads();
    }
  }

#pragma unroll
  for (int bi = 0; bi < 2; ++bi)
#pragma unroll
    for (int i = 0; i < 4; ++i) {
#pragma unroll
      for (int j = 0; j < 4; ++j) {
        int jj = j0 + wn*64 + j*16 + l15;
        if (jj < OUTN) {
          size_t rowbase = (size_t)(bi*256 + wm*64 + i*16 + lq*4);
#pragma unroll
          for (int q = 0; q < 4; ++q)
            out[(rowbase + q)*OUTN + jj] = acc[bi][i][j][q];
        }
      }
    }
}

extern "C" void kernel_launch(void* const* d_in, const int* in_sizes, int n_in,
                              void* d_out, int out_size, void* d_ws, size_t ws_size,
                              hipStream_t stream)
{
  const int*   items  = (const int*)  d_in[0];
  const float* A      = (const float*)d_in[1];
  const int*   alias  = (const int*)  d_in[2];
  const float* emb    = (const float*)d_in[3];
  const float* w_ih   = (const float*)d_in[4];
  const float* w_hh   = (const float*)d_in[5];
  const float* b_ih   = (const float*)d_in[6];
  const float* b_hh   = (const float*)d_in[7];
  const float* b_iah  = (const float*)d_in[8];
  const float* b_oah  = (const float*)d_in[9];
  const float* W_ein  = (const float*)d_in[10];
  const float* b_ein  = (const float*)d_in[11];
  const float* W_eout = (const float*)d_in[12];
  const float* b_eout = (const float*)d_in[13];
  const float* W1     = (const float*)d_in[14];
  const float* b1     = (const float*)d_in[15];
  const float* W2     = (const float*)d_in[16];
  const float* b2     = (const float*)d_in[17];
  const float* W3     = (const float*)d_in[18];
  const float* Wt     = (const float*)d_in[19];
  const float* bt_    = (const float*)d_in[20];

  char*  wsb  = (char*)d_ws;
  float* outf = (float*)d_out;

  k0_prep<<<240, 256, 0, stream>>>(w_ih, w_hh, W_ein, W_eout, W1, W2, Wt, wsb);

  k1ab<<<NB, 512, 130368, stream>>>(items, A, emb, b_ein, b_eout, b_iah, b_oah, wsb, outf);

  k1cd_gru2<<<200, 512, 131072, stream>>>(wsb, b_ih, b_hh, outf);

  k1e_attn<<<NB, 256, 55584, stream>>>(alias, b1, b2, W3, bt_, wsb, outf);

  k2_mfma<<<dim3(782, 1), 512, 98304, stream>>>(emb, (const char*)d_ws, outf);
}

// Round 6
// 206.880 us; speedup vs baseline: 1.1464x; 1.1464x over previous
//
#include <hip/hip_runtime.h>

#define NB   512
#define NN   50
#define LLn  50
#define HD   128
#define OUTN 99999

// ---------------- ws byte offsets ----------------
#define WS_W1T   0         // fp32 [128][128] transposed
#define WS_W2T   65536     // fp32 [128][128] transposed
#define WS_WTT   131072    // fp32 [256][128] transposed
#define WS_WEH   262144    // bf16 hi [256 n][128 k]  (rows 0-127 W_ein, 128-255 W_eout)
#define WS_WEL   327680    // bf16 lo
#define WS_WCATH 393216    // bf16 hi [384 n][384 k]  (k<256 w_ih, k>=256 w_hh)
#define WS_WCATL 688128    // bf16 lo
#define WS_AHI   983040    // a-final hi image [2 kh][512 b][128 B]
#define WS_ALO   1114112

typedef __attribute__((ext_vector_type(8))) short bf16x8;
typedef __attribute__((ext_vector_type(4))) float f32x4;

__device__ __forceinline__ unsigned short f2bf(float f) {
  unsigned int u = __float_as_uint(f);
  unsigned int r = (u + 0x7FFFu + ((u >> 16) & 1u)) >> 16;
  return (unsigned short)r;
}
__device__ __forceinline__ float bf2f(unsigned short h) {
  return __uint_as_float(((unsigned int)h) << 16);
}
__device__ __forceinline__ void cvt4(float4 v, ushort4& hi, ushort4& lo) {
  unsigned short h0 = f2bf(v.x), h1 = f2bf(v.y), h2 = f2bf(v.z), h3 = f2bf(v.w);
  hi = make_ushort4(h0, h1, h2, h3);
  lo = make_ushort4(f2bf(v.x - bf2f(h0)), f2bf(v.y - bf2f(h1)),
                    f2bf(v.z - bf2f(h2)), f2bf(v.w - bf2f(h3)));
}
__device__ __forceinline__ void gl_lds16(const void* g, void* l) {
  __builtin_amdgcn_global_load_lds(
      (const __attribute__((address_space(1))) void*)g,
      (__attribute__((address_space(3))) void*)l, 16, 0, 0);
}
__device__ __forceinline__ float sigm(float x) { return 1.f/(1.f + __expf(-x)); }

// ================= k0: weight prep (unchanged) =================
__global__ void k0_prep(const float* __restrict__ w_ih, const float* __restrict__ w_hh,
                        const float* __restrict__ W_ein, const float* __restrict__ W_eout,
                        const float* __restrict__ W1, const float* __restrict__ W2,
                        const float* __restrict__ Wt, char* __restrict__ wsb)
{
  float* wsf = (float*)wsb;
  for (int i = blockIdx.x * blockDim.x + threadIdx.x; i < 245760; i += gridDim.x * blockDim.x) {
    int idx = i;
    if (idx < 16384) { int k = idx >> 7, c = idx & 127; wsf[idx] = W1[c*128 + k]; continue; }
    idx -= 16384;
    if (idx < 16384) { int k = idx >> 7, c = idx & 127; wsf[16384 + idx] = W2[c*128 + k]; continue; }
    idx -= 16384;
    if (idx < 32768) { int k = idx >> 7, c = idx & 127; wsf[32768 + idx] = Wt[c*256 + k]; continue; }
    idx -= 32768;
    if (idx < 32768) {
      int n = idx >> 7, k = idx & 127;
      float v = (n < 128) ? W_ein[n*128 + k] : W_eout[(n-128)*128 + k];
      unsigned short h = f2bf(v);
      *(unsigned short*)(wsb + WS_WEH + idx*2) = h;
      *(unsigned short*)(wsb + WS_WEL + idx*2) = f2bf(v - bf2f(h));
      continue;
    }
    idx -= 32768;
    {
      int n = idx / 384, k = idx % 384;
      float v = (k < 256) ? w_ih[n*256 + k] : w_hh[n*128 + (k - 256)];
      unsigned short h = f2bf(v);
      *(unsigned short*)(wsb + WS_WCATH + idx*2) = h;
      *(unsigned short*)(wsb + WS_WCATL + idx*2) = f2bf(v - bf2f(h));
    }
  }
}

// ================= k1f: fully fused per-sample GNN+GRU+attention =================
// One block per sample, 512 threads, ~156 KB LDS. All intermediates LDS-resident.
__global__ __launch_bounds__(512) void k1f(const int* __restrict__ items,
    const float* __restrict__ A, const float* __restrict__ emb,
    const int* __restrict__ alias_in,
    const float* __restrict__ b_ein, const float* __restrict__ b_eout,
    const float* __restrict__ b_iah, const float* __restrict__ b_oah,
    const float* __restrict__ b_ih, const float* __restrict__ b_hh,
    const float* __restrict__ b1, const float* __restrict__ b2,
    const float* __restrict__ W3, const float* __restrict__ bt_,
    char* __restrict__ wsb)
{
  extern __shared__ char lds[];
  char*  HH   = lds;                       // [64][128] bf16 hi, swizzled  16384
  char*  HL   = lds + 16384;               // lo                           16384
  float* ALDS = (float*)(lds + 32768);     // A_l [2][50][52] fp32         20800
  float* HEf  = (float*)(lds + 53568);     // he fp32 [50][256]            51200
  float* INf  = (float*)(lds + 104768);    // inputs fp32 [50][256]        51200  -> 155968
  char*  STGH = lds + 53568;               // stage bf16 hi [64][128] (reuses HE)
  char*  STGL = lds + 53568 + 16384;
  float* H2f  = (float*)(lds + 104768);    // new hidden [50][132] (reuses IN)
  float* SIG  = (float*)(lds + 53568);     // sig [50][132] (reuses STG)
  float* Q1P  = (float*)(lds + 86336);     // 512 f
  float* AP   = (float*)(lds + 88384);     // 512 f
  float* RP   = (float*)(lds + 90432);     // 512 f
  float* ALP  = (float*)(lds + 92480);     // 64 f
  int*   ALI  = (int*)(lds + 92736);       // 64 i

  const int b = blockIdx.x, tid = threadIdx.x;
  const int lane = tid & 63, wid = tid >> 6, l15 = lane & 15, lq = lane >> 4;

  // ---- P1: load adjacency + gather embedding -> HH/HL (swizzled bf16 hi/lo) ----
  {
    const float* Ab = A + (size_t)b*NN*100;
    for (int i = tid; i < 5000; i += 512) {
      int n = i / 100, cc = i % 100;
      int s_ = (cc >= 50) ? 1 : 0, m = cc - s_*50;
      ALDS[s_*2600 + n*52 + m] = Ab[i];
    }
    for (int i = tid; i < 1600; i += 512) {
      int row = i >> 5, part = i & 31;
      int it = items[b*NN + row];
      float4 v = *(const float4*)&emb[(size_t)it*128 + part*4];
      ushort4 h4, g4;
      cvt4(v, h4, g4);
      unsigned off = row*256 + (((unsigned)(part*8)) ^ (((unsigned)(row&7)) << 4));
      *(ushort4*)(HH + off) = h4;
      *(ushort4*)(HL + off) = g4;
    }
    for (int i = tid; i < 224; i += 512) {
      int row = 50 + (i >> 4), part = i & 15;
      unsigned off = row*256 + (((unsigned)(part*16)) ^ (((unsigned)(row&7)) << 4));
      *(ushort4*)(HH + off) = make_ushort4(0,0,0,0);
      *(ushort4*)(HL + off) = make_ushort4(0,0,0,0);
    }
  }
  __syncthreads();

  // ---- P2: he GEMM (M=64, N=256, K=128), 8 waves x 32 cols ----
  {
    f32x4 acc2[4][2];
#pragma unroll
    for (int i = 0; i < 4; ++i) { acc2[i][0] = (f32x4){0,0,0,0}; acc2[i][1] = (f32x4){0,0,0,0}; }
    for (int s = 0; s < 4; ++s) {
      bf16x8 ah[4], al[4];
#pragma unroll
      for (int i = 0; i < 4; ++i) {
        int row = i*16 + l15;
        unsigned off = row*256 + (((unsigned)(s*64 + lq*16)) ^ (((unsigned)(row&7)) << 4));
        ah[i] = *(const bf16x8*)(HH + off);
        al[i] = *(const bf16x8*)(HL + off);
      }
#pragma unroll
      for (int j = 0; j < 2; ++j) {
        int n = wid*32 + j*16 + l15;
        unsigned boff = (unsigned)(n*256 + s*64 + lq*16);
        bf16x8 bh = *(const bf16x8*)(wsb + WS_WEH + boff);
        bf16x8 bl = *(const bf16x8*)(wsb + WS_WEL + boff);
#pragma unroll
        for (int i = 0; i < 4; ++i) {
          acc2[i][j] = __builtin_amdgcn_mfma_f32_16x16x32_bf16(ah[i], bh, acc2[i][j], 0,0,0);
          acc2[i][j] = __builtin_amdgcn_mfma_f32_16x16x32_bf16(ah[i], bl, acc2[i][j], 0,0,0);
          acc2[i][j] = __builtin_amdgcn_mfma_f32_16x16x32_bf16(al[i], bh, acc2[i][j], 0,0,0);
        }
      }
    }
#pragma unroll
    for (int j = 0; j < 2; ++j) {
      int n = wid*32 + j*16 + l15;
      float bias = (n < 128) ? b_ein[n] : b_eout[n - 128];
#pragma unroll
      for (int i = 0; i < 4; ++i) {
        int rb = i*16 + lq*4;
#pragma unroll
        for (int q = 0; q < 4; ++q) {
          int row = rb + q;
          if (row < 50) HEf[row*256 + n] = acc2[i][j][q] + bias;
        }
      }
    }
  }
  __syncthreads();

  // ---- P3: IN = A @ he + bias (VALU, fp32) ----
  {
    const int c = tid & 127, sel = (tid >> 7) & 1, th = tid >> 8;
    const float* Asel = ALDS + sel*2600;
    const float* hes  = HEf + sel*128 + c;
    const int nbase = th*25;
    float acc[25];
#pragma unroll
    for (int n = 0; n < 25; ++n) acc[n] = 0.f;
    for (int m4 = 0; m4 < 48; m4 += 4) {
      float x0 = hes[(m4+0)*256], x1 = hes[(m4+1)*256];
      float x2 = hes[(m4+2)*256], x3 = hes[(m4+3)*256];
#pragma unroll
      for (int n = 0; n < 25; ++n) {
        float4 a = *(const float4*)&Asel[(nbase+n)*52 + m4];
        acc[n] += a.x*x0 + a.y*x1 + a.z*x2 + a.w*x3;
      }
    }
    {
      float x0 = hes[48*256], x1 = hes[49*256];
#pragma unroll
      for (int n = 0; n < 25; ++n)
        acc[n] += Asel[(nbase+n)*52 + 48]*x0 + Asel[(nbase+n)*52 + 49]*x1;
    }
    float bias = sel ? b_oah[c] : b_iah[c];
#pragma unroll
    for (int n = 0; n < 25; ++n)
      INf[(nbase+n)*256 + sel*128 + c] = acc[n] + bias;
  }
  __syncthreads();

  // ---- P4: cat-GEMM [IN | H] @ [w_ih|w_hh]^T (M=64, N=384, K=384) + GRU ----
  f32x4 accRI[4][2], accNi[4], accNh[4];
#pragma unroll
  for (int i = 0; i < 4; ++i) {
    accRI[i][0] = (f32x4){0,0,0,0}; accRI[i][1] = (f32x4){0,0,0,0};
    accNi[i] = (f32x4){0,0,0,0};    accNh[i] = (f32x4){0,0,0,0};
  }

  for (int kh = 0; kh < 3; ++kh) {
    const char* AH;
    const char* AL;
    if (kh < 2) {
      if (kh == 1) __syncthreads();   // kh=0 MFMA reads of STG done before restage
      for (int i2 = tid; i2 < 2048; i2 += 512) {
        int row = i2 >> 5, part = i2 & 31;
        float4 v = (row < 50) ? *(const float4*)&INf[row*256 + kh*128 + part*4]
                              : make_float4(0.f,0.f,0.f,0.f);
        ushort4 h4, g4;
        cvt4(v, h4, g4);
        unsigned off = row*256 + (((unsigned)(part*8)) ^ (((unsigned)(row&7)) << 4));
        *(ushort4*)(STGH + off) = h4;
        *(ushort4*)(STGL + off) = g4;
      }
      __syncthreads();
      AH = STGH; AL = STGL;
    } else {
      AH = HH; AL = HL;               // H chunk already staged since P1
    }

    for (int s = 0; s < 4; ++s) {
      bf16x8 ah[4], al[4];
#pragma unroll
      for (int i = 0; i < 4; ++i) {
        int row = i*16 + l15;
        unsigned off = row*256 + (((unsigned)(s*64 + lq*16)) ^ (((unsigned)(row&7)) << 4));
        ah[i] = *(const bf16x8*)(AH + off);
        al[i] = *(const bf16x8*)(AL + off);
      }
      const int ng = wid*16 + l15;
#pragma unroll
      for (int g = 0; g < 2; ++g) {
        int n = g*128 + ng;
        unsigned boff = (unsigned)(n*768 + kh*256 + s*64 + lq*16);
        bf16x8 bh = *(const bf16x8*)(wsb + WS_WCATH + boff);
        bf16x8 bl = *(const bf16x8*)(wsb + WS_WCATL + boff);
#pragma unroll
        for (int i = 0; i < 4; ++i) {
          accRI[i][g] = __builtin_amdgcn_mfma_f32_16x16x32_bf16(ah[i], bh, accRI[i][g], 0,0,0);
          accRI[i][g] = __builtin_amdgcn_mfma_f32_16x16x32_bf16(ah[i], bl, accRI[i][g], 0,0,0);
          accRI[i][g] = __builtin_amdgcn_mfma_f32_16x16x32_bf16(al[i], bh, accRI[i][g], 0,0,0);
        }
      }
      {
        int n = 256 + ng;
        unsigned boff = (unsigned)(n*768 + kh*256 + s*64 + lq*16);
        bf16x8 bh = *(const bf16x8*)(wsb + WS_WCATH + boff);
        bf16x8 bl = *(const bf16x8*)(wsb + WS_WCATL + boff);
        if (kh < 2) {
#pragma unroll
          for (int i = 0; i < 4; ++i) {
            accNi[i] = __builtin_amdgcn_mfma_f32_16x16x32_bf16(ah[i], bh, accNi[i], 0,0,0);
            accNi[i] = __builtin_amdgcn_mfma_f32_16x16x32_bf16(ah[i], bl, accNi[i], 0,0,0);
            accNi[i] = __builtin_amdgcn_mfma_f32_16x16x32_bf16(al[i], bh, accNi[i], 0,0,0);
          }
        } else {
#pragma unroll
          for (int i = 0; i < 4; ++i) {
            accNh[i] = __builtin_amdgcn_mfma_f32_16x16x32_bf16(ah[i], bh, accNh[i], 0,0,0);
            accNh[i] = __builtin_amdgcn_mfma_f32_16x16x32_bf16(ah[i], bl, accNh[i], 0,0,0);
            accNh[i] = __builtin_amdgcn_mfma_f32_16x16x32_bf16(al[i], bh, accNh[i], 0,0,0);
          }
        }
      }
    }
  }

  // GRU pointwise epilogue -> H2 (overwrites IN region; IN dead after kh=1 staging)
  {
    const int c = wid*16 + l15;
    float bir = b_ih[c], bii = b_ih[128+c], bin_ = b_ih[256+c];
    float bhr = b_hh[c], bhi = b_hh[128+c], bhn  = b_hh[256+c];
#pragma unroll
    for (int i = 0; i < 4; ++i) {
#pragma unroll
      for (int q = 0; q < 4; ++q) {
        int row = i*16 + lq*4 + q;
        if (row < 50) {
          float rg = sigm(accRI[i][0][q] + bir + bhr);
          float ig = sigm(accRI[i][1][q] + bii + bhi);
          float ng_ = tanhf(accNi[i][q] + bin_ + rg*(accNh[i][q] + bhn));
          unsigned byte = row*256 + (((unsigned)(c*2)) ^ (((unsigned)(row&7)) << 4));
          float h = bf2f(*(const unsigned short*)(HH + byte))
                  + bf2f(*(const unsigned short*)(HL + byte));
          H2f[row*132 + c] = ng_ + ig*(h - ng_);
        }
      }
    }
  }
  if (tid < LLn) ALI[tid] = alias_in[b*LLn + tid];
  __syncthreads();

  // ---- P5: attention readout (4-way k/l split over 512 threads) ----
  int cnt = 0;
  for (int l = 0; l < LLn; ++l) cnt += (ALI[l] > 0) ? 1 : 0;
  int last = cnt - 1; if (last < 0) last = LLn - 1;
  const int a_last = ALI[last];

  const int c = tid & 127, h4 = tid >> 7;
  const float* W1T = (const float*)(wsb + WS_W1T);
  const float* W2T = (const float*)(wsb + WS_W2T);
  const float* WtT = (const float*)(wsb + WS_WTT);

  { // q1 partial over k-quarter
    float q = 0.f;
    for (int k = h4*32; k < h4*32 + 32; k += 4) {
      float4 x = *(const float4*)&H2f[a_last*132 + k];
      q += x.x*W1T[(k<<7)+c] + x.y*W1T[((k+1)<<7)+c]
         + x.z*W1T[((k+2)<<7)+c] + x.w*W1T[((k+3)<<7)+c];
    }
    Q1P[h4*128 + c] = q;
  }
  __syncthreads();

  { // q2 + sigmoid: rows l = h4 + 4*ii
    int al_[13];
#pragma unroll
    for (int ii = 0; ii < 13; ++ii) {
      int l = h4 + 4*ii;
      al_[ii] = (l < LLn) ? ALI[l] : 0;
    }
    float q2a[13];
#pragma unroll
    for (int ii = 0; ii < 13; ++ii) q2a[ii] = 0.f;
    for (int k = 0; k < HD; k += 4) {
      float w0 = W2T[(k<<7)+c],     w1 = W2T[((k+1)<<7)+c];
      float w2 = W2T[((k+2)<<7)+c], w3 = W2T[((k+3)<<7)+c];
#pragma unroll
      for (int ii = 0; ii < 13; ++ii) {
        float4 x = *(const float4*)&H2f[al_[ii]*132 + k];
        q2a[ii] += x.x*w0; q2a[ii] += x.y*w1; q2a[ii] += x.z*w2; q2a[ii] += x.w*w3;
      }
    }
    float q1c = Q1P[c] + Q1P[128+c] + Q1P[256+c] + Q1P[384+c] + b1[c] + b2[c];
#pragma unroll
    for (int ii = 0; ii < 13; ++ii) {
      int l = h4 + 4*ii;
      if (l < LLn) SIG[l*132 + c] = sigm(q1c + q2a[ii]);
    }
  }
  __syncthreads();

  if (tid < 400) { // alpha = sig @ W3, 8 threads/row
    int l = tid >> 3, qd = tid & 7;
    float sum = 0.f;
    for (int cc = qd*16; cc < qd*16 + 16; cc += 4) {
      float4 x = *(const float4*)&SIG[l*132 + cc];
      sum += x.x*W3[cc] + x.y*W3[cc+1] + x.z*W3[cc+2] + x.w*W3[cc+3];
    }
    sum += __shfl_xor(sum, 1);
    sum += __shfl_xor(sum, 2);
    sum += __shfl_xor(sum, 4);
    if (qd == 0) ALP[l] = (ALI[l] > 0) ? sum : 0.f;
  }
  __syncthreads();

  { // a partial over l-quarter
    float acc = 0.f;
    int l0 = h4*13, l1 = l0 + 13; if (l1 > LLn) l1 = LLn;
    for (int l = l0; l < l1; ++l)
      acc += ALP[l] * H2f[ALI[l]*132 + c];
    AP[h4*128 + c] = acc;
  }
  __syncthreads();

  { // final r partial over k-quarter
    float r = 0.f;
    for (int k = h4*32; k < h4*32 + 32; ++k) {
      float av = AP[k] + AP[128+k] + AP[256+k] + AP[384+k];
      r += av * WtT[(k<<7) + c] + H2f[a_last*132 + k] * WtT[((128+k)<<7) + c];
    }
    RP[h4*128 + c] = r;
  }
  __syncthreads();

  if (tid < 128) {
    float r = bt_[c] + RP[c] + RP[128+c] + RP[256+c] + RP[384+c];
    int kh = c >> 6, kl = c & 63;
    unsigned int cb = (unsigned int)(kl*2) ^ (((unsigned int)(b & 7)) << 4);
    unsigned short hi = f2bf(r);
    unsigned short lo = f2bf(r - bf2f(hi));
    *(unsigned short*)(wsb + WS_AHI + kh*65536 + b*128 + cb) = hi;
    *(unsigned short*)(wsb + WS_ALO + kh*65536 + b*128 + cb) = lo;
  }
}

// ================= k2: scores GEMM (unchanged, proven) =================
__global__ __launch_bounds__(512) void k2_mfma(const float* __restrict__ emb,
                                               const char* __restrict__ wsb,
                                               float* __restrict__ out)
{
  extern __shared__ char ldsc[];
  char* AHI = ldsc;
  char* ALO = ldsc + 32768;
  char* EHI = ldsc + 65536;
  char* ELO = ldsc + 81920;

  const int tid  = threadIdx.x;
  const int lane = tid & 63;
  const int wid  = tid >> 6;
  const int wm   = wid >> 1;
  const int wn   = wid & 1;
  const int j0   = blockIdx.x * 128;
  const int l15  = lane & 15, lq = lane >> 4;

  f32x4 acc[2][4][4];
#pragma unroll
  for (int bi = 0; bi < 2; ++bi)
#pragma unroll
    for (int i = 0; i < 4; ++i)
#pragma unroll
      for (int j = 0; j < 4; ++j) acc[bi][i][j] = (f32x4){0.f, 0.f, 0.f, 0.f};

  for (int kh = 0; kh < 2; ++kh) {
    {
      int rbase = tid >> 4, c4 = tid & 15;
#pragma unroll
      for (int rr = 0; rr < 4; ++rr) {
        int row = rbase + rr*32;
        int j = j0 + row; if (j > OUTN - 1) j = OUTN - 1;
        float4 v = *(const float4*)&emb[(size_t)(1 + j)*HD + kh*64 + c4*4];
        ushort4 hi4, lo4;
        cvt4(v, hi4, lo4);
        unsigned int off = (unsigned int)(row*128) + (((unsigned int)(c4*8)) ^ (((unsigned int)(row&7)) << 4));
        *(ushort4*)(EHI + off) = hi4;
        *(ushort4*)(ELO + off) = lo4;
      }
    }
#pragma unroll
    for (int bi = 0; bi < 2; ++bi) {
      const char* srcH = wsb + WS_AHI + kh*65536 + bi*32768;
      const char* srcL = wsb + WS_ALO + kh*65536 + bi*32768;
#pragma unroll
      for (int r = 0; r < 4; ++r) {
        int off = (r*512 + tid) * 16;
        gl_lds16(srcH + off, AHI + off);
        gl_lds16(srcL + off, ALO + off);
      }
      __syncthreads();

#pragma unroll
      for (int s = 0; s < 2; ++s) {
        bf16x8 ah[4], al[4], bh[4], bl[4];
        const unsigned int cb = (unsigned int)(s*64 + (lq << 4));
#pragma unroll
        for (int i = 0; i < 4; ++i) {
          int row = wm*64 + i*16 + l15;
          unsigned int off = (unsigned int)(row*128) + (cb ^ (((unsigned int)(row&7)) << 4));
          ah[i] = *(const bf16x8*)(AHI + off);
          al[i] = *(const bf16x8*)(ALO + off);
        }
#pragma unroll
        for (int j = 0; j < 4; ++j) {
          int row = wn*64 + j*16 + l15;
          unsigned int off = (unsigned int)(row*128) + (cb ^ (((unsigned int)(row&7)) << 4));
          bh[j] = *(const bf16x8*)(EHI + off);
          bl[j] = *(const bf16x8*)(ELO + off);
        }
#pragma unroll
        for (int i = 0; i < 4; ++i)
#pragma unroll
          for (int j = 0; j < 4; ++j) {
            acc[bi][i][j] = __builtin_amdgcn_mfma_f32_16x16x32_bf16(ah[i], bh[j], acc[bi][i][j], 0, 0, 0);
            acc[bi][i][j] = __builtin_amdgcn_mfma_f32_16x16x32_bf16(ah[i], bl[j], acc[bi][i][j], 0, 0, 0);
            acc[bi][i][j] = __builtin_amdgcn_mfma_f32_16x16x32_bf16(al[i], bh[j], acc[bi][i][j], 0, 0, 0);
          }
      }
      __syncthreads();
    }
  }

#pragma unroll
  for (int bi = 0; bi < 2; ++bi)
#pragma unroll
    for (int i = 0; i < 4; ++i) {
#pragma unroll
      for (int j = 0; j < 4; ++j) {
        int jj = j0 + wn*64 + j*16 + l15;
        if (jj < OUTN) {
          size_t rowbase = (size_t)(bi*256 + wm*64 + i*16 + lq*4);
#pragma unroll
          for (int q = 0; q < 4; ++q)
            out[(rowbase + q)*OUTN + jj] = acc[bi][i][j][q];
        }
      }
    }
}

extern "C" void kernel_launch(void* const* d_in, const int* in_sizes, int n_in,
                              void* d_out, int out_size, void* d_ws, size_t ws_size,
                              hipStream_t stream)
{
  const int*   items  = (const int*)  d_in[0];
  const float* A      = (const float*)d_in[1];
  const int*   alias  = (const int*)  d_in[2];
  const float* emb    = (const float*)d_in[3];
  const float* w_ih   = (const float*)d_in[4];
  const float* w_hh   = (const float*)d_in[5];
  const float* b_ih   = (const float*)d_in[6];
  const float* b_hh   = (const float*)d_in[7];
  const float* b_iah  = (const float*)d_in[8];
  const float* b_oah  = (const float*)d_in[9];
  const float* W_ein  = (const float*)d_in[10];
  const float* b_ein  = (const float*)d_in[11];
  const float* W_eout = (const float*)d_in[12];
  const float* b_eout = (const float*)d_in[13];
  const float* W1     = (const float*)d_in[14];
  const float* b1     = (const float*)d_in[15];
  const float* W2     = (const float*)d_in[16];
  const float* b2     = (const float*)d_in[17];
  const float* W3     = (const float*)d_in[18];
  const float* Wt     = (const float*)d_in[19];
  const float* bt_    = (const float*)d_in[20];

  char*  wsb  = (char*)d_ws;
  float* outf = (float*)d_out;

  k0_prep<<<240, 256, 0, stream>>>(w_ih, w_hh, W_ein, W_eout, W1, W2, Wt, wsb);

  k1f<<<NB, 512, 155968, stream>>>(items, A, emb, alias, b_ein, b_eout, b_iah, b_oah,
                                   b_ih, b_hh, b1, b2, W3, bt_, wsb);

  k2_mfma<<<dim3(782, 1), 512, 98304, stream>>>(emb, (const char*)d_ws, outf);
}